// Round 10
// baseline (400.692 us; speedup 1.0000x reference)
//
#include <hip/hip_runtime.h>
#include <hip/hip_bf16.h>

// Problem constants
#define D       512       // embedding dim (= C)
#define K       2048      // codebook size
#define HW      1024      // 32*32
#define N_TOK   16384     // 16*HW
#define NUMEL   8388608   // 16*512*32*32

typedef __attribute__((ext_vector_type(8))) short  short8;   // 8 bf16 = 4 VGPRs
typedef __attribute__((ext_vector_type(4))) float  floatx4;

// async global->LDS DMA, 16 B per lane; LDS dest is wave-uniform base + lane*16
#define GLD_LDS16(gptr, lptr) \
    __builtin_amdgcn_global_load_lds((const __attribute__((address_space(1))) void*)(gptr), \
                                     (__attribute__((address_space(3))) void*)(lptr), 16, 0, 0)

// ---- ws layout (bytes) ----
// zb is TILED: [b][cg][1024 tok][64 ch] bf16 (16*8*1024*64*2 = 16777216 B).
#define WS_ZB    0           // bf16 tiled z (see above)
#define WS_EB    16777216    // bf16 [2048][512]
#define WS_ESQ   18874368    // f32  [2048]
#define WS_MINB  18882560    // u32  [16384] packed (21-bit dist key | 11-bit idx); init in kp
#define WS_PZ    18948096    // f32  [512]  per-kp-block sum z^2 partials (plain writes)
#define WS_PARTS 18956288    // f32  [256]  per-image decoded-key partials (16 used)
#define WS_CNT2  18957312    // u32  [1]    completion counter (zeroed by kp)

// monotone fp32 -> sortable u32, and its inverse
__device__ __forceinline__ unsigned int fkey(float f) {
    unsigned int b = __float_as_uint(f);
    return b ^ ((unsigned int)((int)b >> 31) | 0x80000000u);
}
__device__ __forceinline__ float unfkey(unsigned int u) {
    unsigned int b = (u & 0x80000000u) ? (u ^ 0x80000000u) : ~u;
    return __uint_as_float(b);
}

// ---------------- Kernel P2: prep with CONTIGUOUS reads and writes (unchanged — control) ----------------
__global__ __launch_bounds__(256) void kp(const float* __restrict__ z,
                                          const float* __restrict__ emb,
                                          __hip_bfloat16* __restrict__ zb,
                                          __hip_bfloat16* __restrict__ eb,
                                          float* __restrict__ esq,
                                          float* __restrict__ pz,
                                          unsigned int* __restrict__ minb,
                                          unsigned int* __restrict__ cnt2) {
    __shared__ float t[64][257];     // 65.8 KB -> 2 blocks/CU
    __shared__ float ls[4];
    int blk = blockIdx.x;
    int tid = threadIdx.x;
    if (blk < 512) {
        if (tid < 32) minb[blk * 32 + tid] = 0xFFFFFFFFu;
        if (blk == 0 && tid == 32) *cnt2 = 0u;
        int b  = blk >> 5;           // image 0..15
        int cg = (blk >> 2) & 7;     // 64-ch group 0..7
        int p  = blk & 3;            // 256-token pass 0..3
        const float* zp = z + ((size_t)(b * 512 + cg * 64)) * HW + p * 256;
        float s = 0.f;
        // read: e = r(64 ch) x c4(64 float4s of 256 tok); per wave = 1 KB contiguous
#pragma unroll
        for (int i = 0; i < 16; ++i) {
            int e = tid + 256 * i;
            int r = e >> 6, c4 = e & 63;
            float4 v = *(const float4*)(zp + (size_t)r * HW + c4 * 4);
            s += v.x * v.x + v.y * v.y + v.z * v.z + v.w * v.w;
            int rot = (c4 >> 3) & 3;  // rotate elems within the 16B granule: kills column conflicts
            t[r][c4 * 4 + ((0 + rot) & 3)] = v.x;
            t[r][c4 * 4 + ((1 + rot) & 3)] = v.y;
            t[r][c4 * 4 + ((2 + rot) & 3)] = v.z;
            t[r][c4 * 4 + ((3 + rot) & 3)] = v.w;
        }
#pragma unroll
        for (int o = 32; o; o >>= 1) s += __shfl_down(s, o);
        if ((tid & 63) == 0) ls[tid >> 6] = s;
        __syncthreads();
        if (tid == 0) pz[blk] = ls[0] + ls[1] + ls[2] + ls[3];
        // write: one contiguous 32 KB tile zb[b][cg][p*256 + tt][ch]
        __hip_bfloat16* op = zb + ((size_t)((b * 8 + cg) * 1024 + p * 256)) * 64;
#pragma unroll
        for (int i = 0; i < 16; ++i) {
            int e = tid + 256 * i;
            int tt = e >> 4, cq = e & 15;      // token 0..255, ch-quad 0..15
            int col = (tt & ~3) + ((tt + (tt >> 5)) & 3);   // inverse of the write rotation
            __hip_bfloat16 q0 = __float2bfloat16(t[cq * 4 + 0][col]);
            __hip_bfloat16 q1 = __float2bfloat16(t[cq * 4 + 1][col]);
            __hip_bfloat16 q2 = __float2bfloat16(t[cq * 4 + 2][col]);
            __hip_bfloat16 q3 = __float2bfloat16(t[cq * 4 + 3][col]);
            ushort4 u;
            u.x = *(unsigned short*)&q0; u.y = *(unsigned short*)&q1;
            u.z = *(unsigned short*)&q2; u.w = *(unsigned short*)&q3;
            *(ushort4*)(op + (size_t)tt * 64 + cq * 4) = u;
        }
    } else {
        // emb prep: 8 rows per block, one 32-lane half-wave per row; coalesced 512 B stores
        int k0 = (blk - 512) * 8;
        int h = tid >> 5, l = tid & 31;
        int row = k0 + h;
        const float* ep = emb + (size_t)row * D;
        __hip_bfloat16* op = eb + (size_t)row * D;
        float s = 0.f;
#pragma unroll
        for (int j = 0; j < 4; ++j) {
            float4 v = *(const float4*)(ep + l * 4 + j * 128);
            s += v.x * v.x + v.y * v.y + v.z * v.z + v.w * v.w;
            __hip_bfloat16 q0 = __float2bfloat16(v.x);
            __hip_bfloat16 q1 = __float2bfloat16(v.y);
            __hip_bfloat16 q2 = __float2bfloat16(v.z);
            __hip_bfloat16 q3 = __float2bfloat16(v.w);
            ushort4 u;
            u.x = *(unsigned short*)&q0; u.y = *(unsigned short*)&q1;
            u.z = *(unsigned short*)&q2; u.w = *(unsigned short*)&q3;
            *(ushort4*)(op + l * 4 + j * 128) = u;
        }
#pragma unroll
        for (int o = 16; o; o >>= 1) s += __shfl_down(s, o, 32);
        if (l == 0) esq[row] = s;
    }
}

// ---------------- Kernel G6: 256x256 tile, BK=32 dbuf, 64 KB LDS -> 2 blocks/CU ----------------
// R9 theory: at 128 KB LDS (1 block/CU) the barrier's vmcnt(0) drain has no co-resident
// block to hide under (m114 mechanism absent). BK 64->32 halves LDS -> 2 blocks/CU,
// 16 waves/CU: the other block's MFMA covers this block's barrier drain. Same 256² tile
// (B-reuse, 32 MFMA : 12 ds_read per step), R1-proven BK=32 swizzle pair
// (store c4^((lane>>3)&3), read lquad^((lrow>>1)&3)), K-rotation (t+2*ntile)&15.
__global__ __launch_bounds__(512, 4) void kg(const __hip_bfloat16* __restrict__ zb,
                                             const __hip_bfloat16* __restrict__ eb,
                                             const float* __restrict__ esq,
                                             unsigned int* __restrict__ minb) {
    __shared__ __hip_bfloat16 As[2][256 * 32];   // 16 KiB per slot
    __shared__ __hip_bfloat16 Bs[2][256 * 32];   // total 64 KiB -> 2 blocks/CU

    int bid   = blockIdx.x;
    int swzb  = (bid & 7) * 64 + (bid >> 3);
    int mtile = swzb >> 3;            // 0..63
    int ntile = swzb & 7;             // 0..7

    int tid  = threadIdx.x;
    int wv   = tid >> 6;              // 0..7
    int lane = tid & 63;
    int wm   = wv >> 2, wnn = wv & 3; // 2x4 wave grid, wave tile 128(M) x 64(N)
    int lrow = lane & 15, lquad = lane >> 4;
    int rl4  = lane >> 2, c4 = lane & 3;     // staging: 16 rows x 4 uint4 per wave-call
    int csw  = c4 ^ ((lane >> 3) & 3);       // store-side swizzled global uint4 col (R1-proven)
    int kR   = (lrow >> 1) & 3;              // read-side swizzle key (R1-proven)

    // tiled zb: K-step kt covers ch-half (kt&1) of ch-group (kt>>1)
    int b8      = (mtile >> 2) * 8;          // image * 8 ch-groups
    int tokbase = (mtile & 3) * 256;         // token offset within image
    const uint4* Ag = (const uint4*)zb;                              // rows of 8 uint4
    const uint4* Bg = (const uint4*)(eb + (size_t)ntile * 256 * D);  // row stride 64 uint4

    floatx4 acc[8][4];
#pragma unroll
    for (int f = 0; f < 8; ++f)
#pragma unroll
        for (int g = 0; g < 4; ++g) acc[f][g] = (floatx4){0.f, 0.f, 0.f, 0.f};

    // K-step rotation: co-XCD blocks sharing an A-tile start at different K-steps
#define TT(t) (((t) + 2 * ntile) & 15)

    // stage K-step kt (32 cols) into slot sl: 2 A-GLD + 2 B-GLD per wave, 16 rows each
#define STAGE(sl, kt) do {                                                                 \
        _Pragma("unroll")                                                                  \
        for (int h = 0; h < 2; ++h) {                                                      \
            int rb = wv * 32 + h * 16;     /* wave-uniform row base */                     \
            GLD_LDS16(Ag + ((size_t)(b8 + ((kt) >> 1)) * 1024 + tokbase + rb + rl4) * 8    \
                          + ((kt) & 1) * 4 + csw,                                          \
                      &As[sl][rb * 32]);                                                   \
            GLD_LDS16(Bg + (size_t)(rb + rl4) * 64 + (kt) * 4 + csw, &Bs[sl][rb * 32]);    \
        }                                                                                  \
    } while (0)

    // compute one 32-K step from slot sl: 4 B-frags + 8 A-frags + 32 MFMA
#define STEP(sl) do {                                                                      \
        short8 bf[4], af[8];                                                               \
        const int cL = (lquad ^ kR) << 3;                                                  \
        _Pragma("unroll")                                                                  \
        for (int g = 0; g < 4; ++g)                                                        \
            bf[g] = *(const short8*)&Bs[sl][(wnn * 64 + g * 16 + lrow) * 32 + cL];         \
        _Pragma("unroll")                                                                  \
        for (int f = 0; f < 8; ++f)                                                        \
            af[f] = *(const short8*)&As[sl][(wm * 128 + f * 16 + lrow) * 32 + cL];         \
        _Pragma("unroll")                                                                  \
        for (int f = 0; f < 8; ++f)                                                        \
            _Pragma("unroll")                                                              \
            for (int g = 0; g < 4; ++g)                                                    \
                acc[f][g] = __builtin_amdgcn_mfma_f32_16x16x32_bf16(af[f], bf[g],          \
                                                                    acc[f][g], 0, 0, 0);   \
    } while (0)

    STAGE(0, TT(0));
    __syncthreads();

#pragma unroll
    for (int t = 0; t < 16; ++t) {
        if (t < 15) STAGE((t + 1) & 1, TT(t + 1));
        STEP(t & 1);
        __syncthreads();
    }
#undef STAGE
#undef STEP
#undef TT

    float es[4];
#pragma unroll
    for (int g = 0; g < 4; ++g) es[g] = esq[ntile * 256 + wnn * 64 + g * 16 + lrow];

    unsigned int* scr = (unsigned int*)&As[0][0];   // 4 KiB scratch
#pragma unroll
    for (int f = 0; f < 8; ++f) {
#pragma unroll
        for (int r = 0; r < 4; ++r) {
            unsigned int best = 0xFFFFFFFFu;
#pragma unroll
            for (int g = 0; g < 4; ++g) {
                float dist = es[g] - 2.0f * acc[f][g][r];
                unsigned int kidx = (unsigned int)(ntile * 256 + wnn * 64 + g * 16 + lrow);
                unsigned int p = (fkey(dist) & 0xFFFFF800u) | kidx;
                best = p < best ? p : best;
            }
#pragma unroll
            for (int o = 1; o < 16; o <<= 1) {
                unsigned int other = (unsigned int)__shfl_xor((int)best, o);
                best = other < best ? other : best;
            }
            if (lrow == 0)
                scr[wnn * 256 + wm * 128 + f * 16 + lquad * 4 + r] = best;
        }
    }
    __syncthreads();
    if (tid < 256) {
        unsigned int b0 = scr[tid];
        unsigned int b1 = scr[256 + tid];
        unsigned int b2 = scr[512 + tid];
        unsigned int b3 = scr[768 + tid];
        b0 = b1 < b0 ? b1 : b0;
        b2 = b3 < b2 ? b3 : b2;
        b0 = b2 < b0 ? b2 : b0;
        atomicMin(&minb[mtile * 256 + tid], b0);
    }
}

// ---------------- Kernel O5: gather + NCHW write + loss, contiguous panels (unchanged — control) ----------------
__global__ __launch_bounds__(256) void ko3(const float* __restrict__ emb,
                                           const unsigned int* __restrict__ minb,
                                           const float* __restrict__ pz,
                                           float* __restrict__ out,
                                           float* __restrict__ parts,
                                           unsigned int* __restrict__ cnt2) {
    __shared__ int   idx[1024];
    __shared__ float qt[8][1024];
    __shared__ float red[4];
    __shared__ int finflag;
    int blk = blockIdx.x;            // 0..1023
    int b   = blk >> 6;              // image 0..15
    int cg  = blk & 63;              // channel group 0..63 (8 channels each)
    int c0  = cg * 8;
    int tid = threadIdx.x;

    if (tid == 0) finflag = 0;

    float lv = 0.f;
#pragma unroll
    for (int i = 0; i < 4; ++i) {
        int t = tid + 256 * i;
        unsigned int key = minb[b * 1024 + t];
        idx[t] = (int)(key & 0x7FFu);
        if (cg == 0) lv += unfkey(key & 0xFFFFF800u);
    }
    __syncthreads();

    if (cg == 0) {
#pragma unroll
        for (int o = 32; o; o >>= 1) lv += __shfl_down(lv, o);
        if ((tid & 63) == 0) red[tid >> 6] = lv;
        __syncthreads();
        if (tid == 0) {
            parts[b] = red[0] + red[1] + red[2] + red[3];
            __threadfence();
            finflag = (atomicAdd(cnt2, 1u) == 15u);
        }
    }

    int half = tid & 1;
    int tb   = tid >> 1;
#pragma unroll
    for (int i = 0; i < 8; ++i) {
        int t = tb + 128 * i;
        float4 v = *(const float4*)(emb + (size_t)idx[t] * D + c0 + half * 4);
        qt[half * 4 + 0][t] = v.x; qt[half * 4 + 1][t] = v.y;
        qt[half * 4 + 2][t] = v.z; qt[half * 4 + 3][t] = v.w;
    }
    __syncthreads();

    float4* ob = (float4*)(out + ((size_t)b * D + c0) * HW);
    const float4* qb = (const float4*)&qt[0][0];
#pragma unroll
    for (int i = 0; i < 8; ++i)
        ob[tid + 256 * i] = qb[tid + 256 * i];

    __syncthreads();
    if (finflag) {
        float sv = (tid < 16) ? atomicAdd(&parts[tid], 0.0f) : 0.f;
        sv += pz[tid] + pz[256 + tid];           // fold 512 z^2 partials
#pragma unroll
        for (int o = 32; o; o >>= 1) sv += __shfl_down(sv, o);
        if ((tid & 63) == 0) red[tid >> 6] = sv;
        __syncthreads();
        if (tid == 0)
            out[NUMEL] = 1.25f * (red[0] + red[1] + red[2] + red[3]) / 8388608.0f;
    }
}

extern "C" void kernel_launch(void* const* d_in, const int* in_sizes, int n_in,
                              void* d_out, int out_size, void* d_ws, size_t ws_size,
                              hipStream_t stream) {
    const float* z   = (const float*)d_in[0];   // [16,512,32,32]
    const float* emb = (const float*)d_in[1];   // [2048,512]
    char* ws = (char*)d_ws;
    __hip_bfloat16* zb   = (__hip_bfloat16*)(ws + WS_ZB);
    __hip_bfloat16* eb   = (__hip_bfloat16*)(ws + WS_EB);
    float*          esq  = (float*)(ws + WS_ESQ);
    unsigned int*   minb = (unsigned int*)(ws + WS_MINB);
    float*          pz   = (float*)(ws + WS_PZ);
    float*          parts= (float*)(ws + WS_PARTS);
    unsigned int*   cnt2 = (unsigned int*)(ws + WS_CNT2);
    float* out = (float*)d_out;

    kp <<< 768, 256, 0, stream>>>(z, emb, zb, eb, esq, pz, minb, cnt2);
    kg <<< 512, 512, 0, stream>>>(zb, eb, esq, minb);
    ko3<<<1024, 256, 0, stream>>>(emb, minb, pz, out, parts, cnt2);
}

// Round 11
// 387.152 us; speedup vs baseline: 1.0350x; 1.0350x over previous
//
#include <hip/hip_runtime.h>
#include <hip/hip_bf16.h>
#include <hip/hip_cooperative_groups.h>
namespace cg = cooperative_groups;

// Problem constants
#define D       512       // embedding dim (= C)
#define K       2048      // codebook size
#define HW      1024      // 32*32
#define NUMEL   8388608   // 16*512*32*32

typedef __attribute__((ext_vector_type(8))) short  short8;   // 8 bf16 = 4 VGPRs
typedef __attribute__((ext_vector_type(4))) float  floatx4;

// async global->LDS DMA, 16 B per lane; LDS dest is wave-uniform base + lane*16
#define GLD_LDS16(gptr, lptr) \
    __builtin_amdgcn_global_load_lds((const __attribute__((address_space(1))) void*)(gptr), \
                                     (__attribute__((address_space(3))) void*)(lptr), 16, 0, 0)

// ---- ws layout (bytes) ----
// zb TILED: [b][cg][1024 tok][64 ch] bf16 (16 MB)
#define WS_ZB    0
#define WS_EB    16777216    // bf16 [2048][512]
#define WS_ESQ   18874368    // f32  [2048]
#define WS_MINB  18882560    // u32  [16384] packed keys
#define WS_PZ    18948096    // f32  [256] per-block z^2 partials
#define WS_PARTS 18956288    // f32  [16]  per-image decoded-key partials

// monotone fp32 -> sortable u32, and its inverse
__device__ __forceinline__ unsigned int fkey(float f) {
    unsigned int b = __float_as_uint(f);
    return b ^ ((unsigned int)((int)b >> 31) | 0x80000000u);
}
__device__ __forceinline__ float unfkey(unsigned int u) {
    unsigned int b = (u & 0x80000000u) ? (u ^ 0x80000000u) : ~u;
    return __uint_as_float(b);
}

// ================= ONE cooperative kernel: prep -> GEMM+argmin -> gather+loss =================
// 256 blocks x 512 thr, exactly 1 block/CU (128 KB LDS). Grid-wide syncs replace the 3-kernel
// pipeline (ledger showed >=29 us of inter-kernel overhead). Phase G is R9's verified G5 body
// (256x256 tile, BK=64 dbuf, XOR swizzle, K-rotation), run twice per block = the same two
// sequential generations the 512-block dispatch already executed.
__global__ __launch_bounds__(512, 2) void fused(const float* __restrict__ z,
                                                const float* __restrict__ emb,
                                                __hip_bfloat16* __restrict__ zb,
                                                __hip_bfloat16* __restrict__ eb,
                                                float* __restrict__ esq,
                                                unsigned int* __restrict__ minb,
                                                float* __restrict__ pz,
                                                float* __restrict__ parts,
                                                float* __restrict__ out) {
    __shared__ __attribute__((aligned(16))) char lds[131072];
    cg::grid_group grid = cg::this_grid();

    const int bid  = blockIdx.x;       // 0..255
    const int tid  = threadIdx.x;      // 0..511
    const int lane = tid & 63;
    const int wv   = tid >> 6;         // 0..7

    // ================= Phase P: prep =================
    if (tid < 64) minb[bid * 64 + tid] = 0xFFFFFFFFu;

    // emb -> eb bf16 + esq : 8 rows per block, one wave per row (coalesced 1 KB per row-pass)
    {
        int row = bid * 8 + wv;
        const float* ep = emb + (size_t)row * D;
        __hip_bfloat16* op = eb + (size_t)row * D;
        float s = 0.f;
#pragma unroll
        for (int j = 0; j < 2; ++j) {
            float4 v = *(const float4*)(ep + lane * 4 + j * 256);
            s += v.x * v.x + v.y * v.y + v.z * v.z + v.w * v.w;
            __hip_bfloat16 q0 = __float2bfloat16(v.x);
            __hip_bfloat16 q1 = __float2bfloat16(v.y);
            __hip_bfloat16 q2 = __float2bfloat16(v.z);
            __hip_bfloat16 q3 = __float2bfloat16(v.w);
            ushort4 u;
            u.x = *(unsigned short*)&q0; u.y = *(unsigned short*)&q1;
            u.z = *(unsigned short*)&q2; u.w = *(unsigned short*)&q3;
            *(ushort4*)(op + lane * 4 + j * 256) = u;
        }
#pragma unroll
        for (int o = 32; o; o >>= 1) s += __shfl_down(s, o);
        if (lane == 0) esq[row] = s;
    }

    // z NCHW -> tiled zb bf16 (+ z^2 partial): 2 tiles of (64 ch x 256 tok) per block
    {
        float* t   = (float*)lds;                 // [64][257] = 65792 B
        float* ls8 = (float*)(lds + 66048);       // 8 floats
        float zs = 0.f;
#pragma unroll 1
        for (int k = 0; k < 2; ++k) {
            int zt  = bid * 2 + k;                // 0..511
            int b   = zt >> 5;                    // image
            int cgp = (zt >> 2) & 7;              // 64-ch group
            int p   = zt & 3;                     // 256-token pass
            const float* zp = z + ((size_t)(b * 512 + cgp * 64)) * HW + p * 256;
            __syncthreads();                      // t reusable (prev writeback reads done)
#pragma unroll
            for (int i = 0; i < 8; ++i) {
                int e = tid + 512 * i;            // 4096 float4s: r(64 ch) x c4(64)
                int r = e >> 6, c4 = e & 63;
                float4 v = *(const float4*)(zp + (size_t)r * HW + c4 * 4);
                zs += v.x * v.x + v.y * v.y + v.z * v.z + v.w * v.w;
                int rot = (c4 >> 3) & 3;          // granule rotation kills column conflicts
                t[r * 257 + c4 * 4 + ((0 + rot) & 3)] = v.x;
                t[r * 257 + c4 * 4 + ((1 + rot) & 3)] = v.y;
                t[r * 257 + c4 * 4 + ((2 + rot) & 3)] = v.z;
                t[r * 257 + c4 * 4 + ((3 + rot) & 3)] = v.w;
            }
            __syncthreads();
            __hip_bfloat16* op = zb + ((size_t)((b * 8 + cgp) * 1024 + p * 256)) * 64;
#pragma unroll
            for (int i = 0; i < 8; ++i) {
                int e = tid + 512 * i;            // tt(256 tok) x cq(16 ch-quads)
                int tt = e >> 4, cq = e & 15;
                int col = (tt & ~3) + ((tt + (tt >> 5)) & 3);   // inverse rotation
                __hip_bfloat16 q0 = __float2bfloat16(t[(cq * 4 + 0) * 257 + col]);
                __hip_bfloat16 q1 = __float2bfloat16(t[(cq * 4 + 1) * 257 + col]);
                __hip_bfloat16 q2 = __float2bfloat16(t[(cq * 4 + 2) * 257 + col]);
                __hip_bfloat16 q3 = __float2bfloat16(t[(cq * 4 + 3) * 257 + col]);
                ushort4 u;
                u.x = *(unsigned short*)&q0; u.y = *(unsigned short*)&q1;
                u.z = *(unsigned short*)&q2; u.w = *(unsigned short*)&q3;
                *(ushort4*)(op + (size_t)tt * 64 + cq * 4) = u;
            }
        }
#pragma unroll
        for (int o = 32; o; o >>= 1) zs += __shfl_down(zs, o);
        __syncthreads();
        if (lane == 0) ls8[wv] = zs;
        __syncthreads();
        if (tid == 0) {
            float s = 0.f;
#pragma unroll
            for (int i = 0; i < 8; ++i) s += ls8[i];
            pz[bid] = s;
        }
    }

    __threadfence();
    grid.sync();

    // ================= Phase G: GEMM + argmin (R9-verified G5 body, 2 generations) =================
    {
        __hip_bfloat16* ASp = (__hip_bfloat16*)lds;             // [2][256*64]
        __hip_bfloat16* BSp = (__hip_bfloat16*)(lds + 65536);   // [2][256*64]
        int wm = wv >> 2, wnn = wv & 3;
        int lrow = lane & 15, lquad = lane >> 4;
        int rl8 = lane >> 3, c8 = lane & 7;
        int csw = c8 ^ (rl8 & 7);
        int swz = lrow & 7;

#pragma unroll 1
        for (int v = 0; v < 2; ++v) {
            int gbid  = bid + v * 256;
            int swzb  = (gbid & 7) * 64 + (gbid >> 3);
            int mtile = swzb >> 3;
            int ntile = swzb & 7;
            int b8      = (mtile >> 2) * 8;
            int tokbase = (mtile & 3) * 256;
            const uint4* Ag = (const uint4*)zb;
            const uint4* Bg = (const uint4*)(eb + (size_t)ntile * 256 * D);

            floatx4 acc[8][4];
#pragma unroll
            for (int f = 0; f < 8; ++f)
#pragma unroll
                for (int g = 0; g < 4; ++g) acc[f][g] = (floatx4){0.f, 0.f, 0.f, 0.f};

#define TT(t_) (((t_) + ntile) & 7)
#define STAGE(sl, kt) do {                                                                 \
        _Pragma("unroll")                                                                  \
        for (int q = 0; q < 4; ++q) {                                                      \
            int rb = wv * 32 + q * 8;                                                      \
            GLD_LDS16(Ag + ((size_t)(b8 + (kt)) * 1024 + tokbase + rb + rl8) * 8 + csw,    \
                      &ASp[(sl) * 16384 + rb * 64]);                                       \
            GLD_LDS16(Bg + (size_t)(rb + rl8) * 64 + (kt) * 8 + csw,                       \
                      &BSp[(sl) * 16384 + rb * 64]);                                       \
        }                                                                                  \
    } while (0)
#define STEP(sl) do {                                                                      \
        _Pragma("unroll")                                                                  \
        for (int kh = 0; kh < 2; ++kh) {                                                   \
            short8 bf[4], af[8];                                                           \
            const int cL = ((kh * 4 + lquad) ^ swz) << 3;                                  \
            _Pragma("unroll")                                                              \
            for (int g = 0; g < 4; ++g)                                                    \
                bf[g] = *(const short8*)&BSp[(sl) * 16384 + (wnn * 64 + g * 16 + lrow) * 64 + cL]; \
            _Pragma("unroll")                                                              \
            for (int f = 0; f < 8; ++f)                                                    \
                af[f] = *(const short8*)&ASp[(sl) * 16384 + (wm * 128 + f * 16 + lrow) * 64 + cL]; \
            _Pragma("unroll")                                                              \
            for (int f = 0; f < 8; ++f)                                                    \
                _Pragma("unroll")                                                          \
                for (int g = 0; g < 4; ++g)                                                \
                    acc[f][g] = __builtin_amdgcn_mfma_f32_16x16x32_bf16(af[f], bf[g],      \
                                                                        acc[f][g], 0, 0, 0);\
        }                                                                                  \
    } while (0)

            STAGE(0, TT(0));
            __syncthreads();
#pragma unroll
            for (int t = 0; t < 8; ++t) {
                if (t < 7) STAGE((t + 1) & 1, TT(t + 1));
                STEP(t & 1);
                __syncthreads();
            }
#undef STAGE
#undef STEP
#undef TT

            float es[4];
#pragma unroll
            for (int g = 0; g < 4; ++g) es[g] = esq[ntile * 256 + wnn * 64 + g * 16 + lrow];

            unsigned int* scr = (unsigned int*)ASp;
#pragma unroll
            for (int f = 0; f < 8; ++f) {
#pragma unroll
                for (int r = 0; r < 4; ++r) {
                    unsigned int best = 0xFFFFFFFFu;
#pragma unroll
                    for (int g = 0; g < 4; ++g) {
                        float dist = es[g] - 2.0f * acc[f][g][r];
                        unsigned int kidx = (unsigned int)(ntile * 256 + wnn * 64 + g * 16 + lrow);
                        unsigned int p = (fkey(dist) & 0xFFFFF800u) | kidx;
                        best = p < best ? p : best;
                    }
#pragma unroll
                    for (int o = 1; o < 16; o <<= 1) {
                        unsigned int other = (unsigned int)__shfl_xor((int)best, o);
                        best = other < best ? other : best;
                    }
                    if (lrow == 0)
                        scr[wnn * 256 + wm * 128 + f * 16 + lquad * 4 + r] = best;
                }
            }
            __syncthreads();
            if (tid < 256) {
                unsigned int b0 = scr[tid];
                unsigned int b1 = scr[256 + tid];
                unsigned int b2 = scr[512 + tid];
                unsigned int b3 = scr[768 + tid];
                b0 = b1 < b0 ? b1 : b0;
                b2 = b3 < b2 ? b3 : b2;
                b0 = b2 < b0 ? b2 : b0;
                atomicMin(&minb[mtile * 256 + tid], b0);
            }
            __syncthreads();                      // scr reads done before next gen's STAGE
        }
    }

    __threadfence();
    grid.sync();

    // ================= Phase O: gather + contiguous NCHW panels + loss partials =================
    {
        int*   idx  = (int*)lds;                  // 4 KB
        float* qt   = (float*)(lds + 4096);       // [8][1024] = 32 KB
        float* red8 = (float*)(lds + 4096 + 32768);
#pragma unroll 1
        for (int v = 0; v < 4; ++v) {
            int obid = bid * 4 + v;               // 0..1023
            int b = obid >> 6, cgp = obid & 63, c0 = cgp * 8;
            __syncthreads();                      // idx/qt reusable
            float lv = 0.f;
#pragma unroll
            for (int i = 0; i < 2; ++i) {
                int tt = tid + 512 * i;
                unsigned int key = minb[b * 1024 + tt];
                idx[tt] = (int)(key & 0x7FFu);
                if (cgp == 0) lv += unfkey(key & 0xFFFFF800u);
            }
            __syncthreads();
            if (cgp == 0) {                       // block-uniform branch
#pragma unroll
                for (int o = 32; o; o >>= 1) lv += __shfl_down(lv, o);
                if (lane == 0) red8[wv] = lv;
                __syncthreads();
                if (tid == 0) {
                    float s = 0.f;
#pragma unroll
                    for (int i = 0; i < 8; ++i) s += red8[i];
                    parts[b] = s;
                }
            }
            // gather: 1024 tokens x 8 ch, 2 lanes per token
            int half = tid & 1, tb = tid >> 1;
#pragma unroll
            for (int i = 0; i < 4; ++i) {
                int tt = tb + 256 * i;
                float4 v4 = *(const float4*)(emb + (size_t)idx[tt] * D + c0 + half * 4);
                qt[(half * 4 + 0) * 1024 + tt] = v4.x;
                qt[(half * 4 + 1) * 1024 + tt] = v4.y;
                qt[(half * 4 + 2) * 1024 + tt] = v4.z;
                qt[(half * 4 + 3) * 1024 + tt] = v4.w;
            }
            __syncthreads();
            // one contiguous 32 KB store
            float4* ob = (float4*)(out + ((size_t)b * D + c0) * HW);
            const float4* qb = (const float4*)qt;
#pragma unroll
            for (int i = 0; i < 4; ++i)
                ob[tid + 512 * i] = qb[tid + 512 * i];
        }
    }

    __threadfence();
    grid.sync();

    // ================= Final: loss reduce by block 0 =================
    if (bid == 0) {
        float sv = 0.f;
        if (tid < 16)  sv  = parts[tid];
        if (tid < 256) sv += pz[tid];
#pragma unroll
        for (int o = 32; o; o >>= 1) sv += __shfl_down(sv, o);
        float* r8 = (float*)lds;
        __syncthreads();
        if (lane == 0) r8[wv] = sv;
        __syncthreads();
        if (tid == 0) {
            float s = 0.f;
#pragma unroll
            for (int i = 0; i < 8; ++i) s += r8[i];
            out[NUMEL] = 1.25f * s / 8388608.0f;
        }
    }
}

extern "C" void kernel_launch(void* const* d_in, const int* in_sizes, int n_in,
                              void* d_out, int out_size, void* d_ws, size_t ws_size,
                              hipStream_t stream) {
    const float* z   = (const float*)d_in[0];   // [16,512,32,32]
    const float* emb = (const float*)d_in[1];   // [2048,512]
    char* ws = (char*)d_ws;
    __hip_bfloat16* zb   = (__hip_bfloat16*)(ws + WS_ZB);
    __hip_bfloat16* eb   = (__hip_bfloat16*)(ws + WS_EB);
    float*          esq  = (float*)(ws + WS_ESQ);
    unsigned int*   minb = (unsigned int*)(ws + WS_MINB);
    float*          pz   = (float*)(ws + WS_PZ);
    float*          parts= (float*)(ws + WS_PARTS);
    float* out = (float*)d_out;

    void* args[] = {(void*)&z, (void*)&emb, (void*)&zb, (void*)&eb, (void*)&esq,
                    (void*)&minb, (void*)&pz, (void*)&parts, (void*)&out};
    hipLaunchCooperativeKernel((const void*)fused, dim3(256), dim3(512), args, 0, stream);
}

// Round 13
// 147.225 us; speedup vs baseline: 2.7216x; 2.6297x over previous
//
#include <hip/hip_runtime.h>
#include <hip/hip_bf16.h>

// Problem constants
#define D       512       // embedding dim (= C)
#define K       2048      // codebook size
#define HW      1024      // 32*32
#define N_TOK   16384     // 16*HW
#define NUMEL   8388608   // 16*512*32*32

typedef __attribute__((ext_vector_type(8))) short  short8;   // 8 bf16 = 4 VGPRs
typedef __attribute__((ext_vector_type(4))) float  floatx4;

// async global->LDS DMA, 16 B per lane; LDS dest is wave-uniform base + lane*16
#define GLD_LDS16(gptr, lptr) \
    __builtin_amdgcn_global_load_lds((const __attribute__((address_space(1))) void*)(gptr), \
                                     (__attribute__((address_space(3))) void*)(lptr), 16, 0, 0)

// ---- ws layout (bytes) ----
#define WS_ZB    0           // bf16 [16384][512] token-major
#define WS_EB    16777216    // bf16 [2048][512]
#define WS_ESQ   18874368    // f32  [2048]
#define WS_MINB  18882560    // u32  [16384] packed (21-bit dist key | 11-bit idx); init in kp
#define WS_PZ    18948096    // f32  [2048] per-kp-block sum z^2 partials (plain writes)
#define WS_PARTS 18956288    // f32  [256]  per-image decoded-key partials (16 used)
#define WS_CNT2  18957312    // u32  [1]    completion counter (zeroed by kp)

// monotone fp32 -> sortable u32, and its inverse
__device__ __forceinline__ unsigned int fkey(float f) {
    unsigned int b = __float_as_uint(f);
    return b ^ ((unsigned int)((int)b >> 31) | 0x80000000u);
}
__device__ __forceinline__ float unfkey(unsigned int u) {
    unsigned int b = (u & 0x80000000u) ? (u ^ 0x80000000u) : ~u;
    return __uint_as_float(b);
}

// ---------------- Kernel P: fused prep (R0-R5 verified) ----------------
// blocks [0,2048): z NCHW fp32 -> zb bf16 (transpose+cast) + sum(z^2) partial + minb/cnt2 init
// blocks [2048,4096): emb row -> eb bf16 + e_sq
__global__ __launch_bounds__(256) void kp(const float* __restrict__ z,
                                          const float* __restrict__ emb,
                                          __hip_bfloat16* __restrict__ zb,
                                          __hip_bfloat16* __restrict__ eb,
                                          float* __restrict__ esq,
                                          float* __restrict__ pz,
                                          unsigned int* __restrict__ minb,
                                          unsigned int* __restrict__ cnt2) {
    int blk = blockIdx.x;
    int tid = threadIdx.x;
    if (blk < 2048) {
        if (tid < 8) minb[blk * 8 + tid] = 0xFFFFFFFFu;
        if (blk == 0 && tid == 8) *cnt2 = 0u;
        __shared__ float t[64][65];
        __shared__ float ls[4];
        int b  = blk >> 7;
        int dt = (blk >> 4) & 7;
        int nt = blk & 15;
        int d0 = dt * 64, n0 = nt * 64;
        const float* zp = z + ((size_t)b * D + d0) * HW + n0;
        float s = 0.f;
#pragma unroll
        for (int i = 0; i < 4; ++i) {
            int e = tid + 256 * i;          // r(64 ch) x c4(16)
            int r = e >> 4, c4 = e & 15;
            float4 v = *(const float4*)(zp + (size_t)r * HW + c4 * 4);
            s += v.x * v.x + v.y * v.y + v.z * v.z + v.w * v.w;
            t[r][c4 * 4 + 0] = v.x; t[r][c4 * 4 + 1] = v.y;
            t[r][c4 * 4 + 2] = v.z; t[r][c4 * 4 + 3] = v.w;
        }
#pragma unroll
        for (int o = 32; o; o >>= 1) s += __shfl_down(s, o);
        if ((tid & 63) == 0) ls[tid >> 6] = s;
        __syncthreads();
        if (tid == 0) pz[blk] = ls[0] + ls[1] + ls[2] + ls[3];
        __hip_bfloat16* op = zb + ((size_t)(b * HW + n0)) * D + d0;
#pragma unroll
        for (int i = 0; i < 4; ++i) {
            int e = tid + 256 * i;          // rn(64 tok) x cd4(16)
            int rn = e >> 4, cd4 = e & 15;
            __hip_bfloat16 q0 = __float2bfloat16(t[cd4 * 4 + 0][rn]);
            __hip_bfloat16 q1 = __float2bfloat16(t[cd4 * 4 + 1][rn]);
            __hip_bfloat16 q2 = __float2bfloat16(t[cd4 * 4 + 2][rn]);
            __hip_bfloat16 q3 = __float2bfloat16(t[cd4 * 4 + 3][rn]);
            ushort4 u;
            u.x = *(unsigned short*)&q0; u.y = *(unsigned short*)&q1;
            u.z = *(unsigned short*)&q2; u.w = *(unsigned short*)&q3;
            *(ushort4*)(op + (size_t)rn * D + cd4 * 4) = u;
        }
    } else {
        int k = blk - 2048;
        const float* ep = emb + (size_t)k * D;
        float s = 0.f;
        for (int d = tid; d < D; d += 256) {
            float v = ep[d];
            s += v * v;
            eb[(size_t)k * D + d] = __float2bfloat16(v);
        }
#pragma unroll
        for (int o = 32; o; o >>= 1) s += __shfl_down(s, o);
        __shared__ float ls[4];
        if ((tid & 63) == 0) ls[tid >> 6] = s;
        __syncthreads();
        if (tid == 0) esq[k] = ls[0] + ls[1] + ls[2] + ls[3];
    }
}

// ---------------- Kernel G2: 256x256 tile, 8-wave, ring-of-4 pipelined (R1-verified, 48.6 us) ----------------
// grid 512 blocks x 512 thr. K split into 16 subtiles of 32; 4-deep LDS ring so subtile s+3
// stages (global_load_lds) while s computes. Boundary: s_waitcnt vmcnt(8) (counted, never 0
// in steady state) + raw s_barrier. XOR swizzle -> 2-way max bank aliasing (free).
// setprio(1) around MFMA clusters. LDS 128 KiB -> 1 block/CU.
__global__ __launch_bounds__(512, 2) void kg(const __hip_bfloat16* __restrict__ zb,
                                             const __hip_bfloat16* __restrict__ eb,
                                             const float* __restrict__ esq,
                                             unsigned int* __restrict__ minb) {
    __shared__ __hip_bfloat16 As[4][256 * 32];   // 4 ring slots, 16 KiB each
    __shared__ __hip_bfloat16 Bs[4][256 * 32];

    // bijective XCD swizzle: XCD x owns mtiles x*8..x*8+7 (A 2MB + B 2MB -> L2-fit)
    int bid   = blockIdx.x;
    int swzb  = (bid & 7) * 64 + (bid >> 3);
    int mtile = swzb >> 3;            // 0..63
    int ntile = swzb & 7;             // 0..7

    int tid  = threadIdx.x;
    int wv   = tid >> 6;              // 0..7
    int lane = tid & 63;
    int wm   = wv >> 2, wnn = wv & 3; // 2x4 wave grid, wave tile 128(M) x 64(N)
    int lrow = lane & 15, lquad = lane >> 4;
    int rl4  = lane >> 2, c4 = lane & 3;       // staging: 16 rows x 4 uint4 per wave-call
    int csw  = c4 ^ ((lane >> 3) & 3);         // pre-swizzled global col; key = (row>>1)&3
    int kR   = (lrow >> 1) & 3;                // read-side swizzle key

    const uint4* Ag = (const uint4*)(zb + (size_t)mtile * 256 * D);  // row stride 64 uint4
    const uint4* Bg = (const uint4*)(eb + (size_t)ntile * 256 * D);

    floatx4 acc[8][4];
#pragma unroll
    for (int f = 0; f < 8; ++f)
#pragma unroll
        for (int g = 0; g < 4; ++g) acc[f][g] = (floatx4){0.f, 0.f, 0.f, 0.f};

    // stage subtile ss into ring slot ss&3: 4 wave-GLDs (A lo/hi, B lo/hi), 16 rows/wave each
#define STAGE(ss) do {                                                                     \
        const int slot_ = (ss) & 3;                                                        \
        const int ko_   = (ss) * 4;                                                        \
        GLD_LDS16(Ag + (size_t)(      wv*16 + rl4) * 64 + ko_ + csw, &As[slot_][(      wv*16) * 32]); \
        GLD_LDS16(Bg + (size_t)(      wv*16 + rl4) * 64 + ko_ + csw, &Bs[slot_][(      wv*16) * 32]); \
        GLD_LDS16(Ag + (size_t)(128 + wv*16 + rl4) * 64 + ko_ + csw, &As[slot_][(128 + wv*16) * 32]); \
        GLD_LDS16(Bg + (size_t)(128 + wv*16 + rl4) * 64 + ko_ + csw, &Bs[slot_][(128 + wv*16) * 32]); \
    } while (0)

    // prologue: fill 3 ring slots; wait subtile 0 landed (1,2 stay in flight)
    STAGE(0); STAGE(1); STAGE(2);
    asm volatile("s_waitcnt vmcnt(8)" ::: "memory");
    __builtin_amdgcn_s_barrier();
    __builtin_amdgcn_sched_barrier(0);

#pragma unroll 16
    for (int s = 0; s < 16; ++s) {
        const int slot = s & 3;
        if (s + 3 < 16) STAGE(s + 3);    // slot (s-1)&3: all reads done before last barrier

        short8 bfr[4], af[4];
#pragma unroll
        for (int g = 0; g < 4; ++g)
            bfr[g] = *(const short8*)&Bs[slot][(wnn * 64 + g * 16 + lrow) * 32 + ((lquad ^ kR) << 3)];
#pragma unroll
        for (int f = 0; f < 4; ++f)
            af[f] = *(const short8*)&As[slot][(wm * 128 + f * 16 + lrow) * 32 + ((lquad ^ kR) << 3)];
        __builtin_amdgcn_s_setprio(1);
#pragma unroll
        for (int f = 0; f < 4; ++f)
#pragma unroll
            for (int g = 0; g < 4; ++g)
                acc[f][g] = __builtin_amdgcn_mfma_f32_16x16x32_bf16(af[f], bfr[g], acc[f][g], 0, 0, 0);
        __builtin_amdgcn_s_setprio(0);
#pragma unroll
        for (int f = 0; f < 4; ++f)
            af[f] = *(const short8*)&As[slot][(wm * 128 + 64 + f * 16 + lrow) * 32 + ((lquad ^ kR) << 3)];
        __builtin_amdgcn_s_setprio(1);
#pragma unroll
        for (int f = 0; f < 4; ++f)
#pragma unroll
            for (int g = 0; g < 4; ++g)
                acc[f + 4][g] = __builtin_amdgcn_mfma_f32_16x16x32_bf16(af[f], bfr[g], acc[f + 4][g], 0, 0, 0);
        __builtin_amdgcn_s_setprio(0);

        // boundary: subtile s+1 must be landed; s+2,s+3 stay in flight (8 loads)
        __builtin_amdgcn_sched_barrier(0);
        if (s < 13)       asm volatile("s_waitcnt vmcnt(8) lgkmcnt(0)" ::: "memory");
        else if (s == 13) asm volatile("s_waitcnt vmcnt(4) lgkmcnt(0)" ::: "memory");
        else if (s == 14) asm volatile("s_waitcnt vmcnt(0) lgkmcnt(0)" ::: "memory");
        if (s < 15) __builtin_amdgcn_s_barrier();
        __builtin_amdgcn_sched_barrier(0);
    }
#undef STAGE

    // ---- epilogue: dist = esq[n] - 2*dot; per-wave 16-lane argmin, LDS combine across
    // the 4 N-waves (1 atomicMin per output row per block) ----
    float es[4];
#pragma unroll
    for (int g = 0; g < 4; ++g) es[g] = esq[ntile * 256 + wnn * 64 + g * 16 + lrow];

    unsigned int* scr = (unsigned int*)&As[0][0];   // 4 KiB scratch, slot 0 dead (last subtile used slot 3)
#pragma unroll
    for (int f = 0; f < 8; ++f) {
#pragma unroll
        for (int r = 0; r < 4; ++r) {
            unsigned int best = 0xFFFFFFFFu;
#pragma unroll
            for (int g = 0; g < 4; ++g) {
                float dist = es[g] - 2.0f * acc[f][g][r];
                unsigned int kidx = (unsigned int)(ntile * 256 + wnn * 64 + g * 16 + lrow);
                unsigned int p = (fkey(dist) & 0xFFFFF800u) | kidx;
                best = p < best ? p : best;
            }
#pragma unroll
            for (int o = 1; o < 16; o <<= 1) {
                unsigned int other = (unsigned int)__shfl_xor((int)best, o);
                best = other < best ? other : best;
            }
            if (lrow == 0)
                scr[wnn * 256 + wm * 128 + f * 16 + lquad * 4 + r] = best;
        }
    }
    __syncthreads();
    if (tid < 256) {
        unsigned int b0 = scr[tid];
        unsigned int b1 = scr[256 + tid];
        unsigned int b2 = scr[512 + tid];
        unsigned int b3 = scr[768 + tid];
        b0 = b1 < b0 ? b1 : b0;
        b2 = b3 < b2 ? b3 : b2;
        b0 = b2 < b0 ? b2 : b0;
        atomicMin(&minb[mtile * 256 + tid], b0);
    }
}

// ---------------- Kernel O5: gather + NCHW write + loss, contiguous panels (R5-verified) ----------------
__global__ __launch_bounds__(256) void ko3(const float* __restrict__ emb,
                                           const unsigned int* __restrict__ minb,
                                           const float* __restrict__ pz,
                                           float* __restrict__ out,
                                           float* __restrict__ parts,
                                           unsigned int* __restrict__ cnt2) {
    __shared__ int   idx[1024];      // 4 KB: codebook index per token of image b
    __shared__ float qt[8][1024];    // 32 KB: [channel][hw] = exact NCHW panel layout
    __shared__ float red[4];
    __shared__ int finflag;
    int blk = blockIdx.x;            // 0..1023
    int b   = blk >> 6;              // image 0..15
    int cg  = blk & 63;              // channel group 0..63 (8 channels each)
    int c0  = cg * 8;
    int tid = threadIdx.x;

    if (tid == 0) finflag = 0;

    float lv = 0.f;
#pragma unroll
    for (int i = 0; i < 4; ++i) {
        int t = tid + 256 * i;
        unsigned int key = minb[b * 1024 + t];
        idx[t] = (int)(key & 0x7FFu);
        if (cg == 0) lv += unfkey(key & 0xFFFFF800u);
    }
    __syncthreads();

    if (cg == 0) {
#pragma unroll
        for (int o = 32; o; o >>= 1) lv += __shfl_down(lv, o);
        if ((tid & 63) == 0) red[tid >> 6] = lv;
        __syncthreads();
        if (tid == 0) {
            parts[b] = red[0] + red[1] + red[2] + red[3];
            __threadfence();
            finflag = (atomicAdd(cnt2, 1u) == 15u);
        }
    }

    int half = tid & 1;
    int tb   = tid >> 1;
#pragma unroll
    for (int i = 0; i < 8; ++i) {
        int t = tb + 128 * i;
        float4 v = *(const float4*)(emb + (size_t)idx[t] * D + c0 + half * 4);
        qt[half * 4 + 0][t] = v.x; qt[half * 4 + 1][t] = v.y;
        qt[half * 4 + 2][t] = v.z; qt[half * 4 + 3][t] = v.w;
    }
    __syncthreads();

    float4* ob = (float4*)(out + ((size_t)b * D + c0) * HW);
    const float4* qb = (const float4*)&qt[0][0];
#pragma unroll
    for (int i = 0; i < 8; ++i)
        ob[tid + 256 * i] = qb[tid + 256 * i];

    __syncthreads();
    if (finflag) {
        float sv = (tid < 16) ? atomicAdd(&parts[tid], 0.0f) : 0.f;
#pragma unroll
        for (int k8 = 0; k8 < 8; ++k8) sv += pz[tid * 8 + k8];   // fold 2048 z^2 partials
#pragma unroll
        for (int o = 32; o; o >>= 1) sv += __shfl_down(sv, o);
        if ((tid & 63) == 0) red[tid >> 6] = sv;
        __syncthreads();
        if (tid == 0)
            out[NUMEL] = 1.25f * (red[0] + red[1] + red[2] + red[3]) / 8388608.0f;
    }
}

extern "C" void kernel_launch(void* const* d_in, const int* in_sizes, int n_in,
                              void* d_out, int out_size, void* d_ws, size_t ws_size,
                              hipStream_t stream) {
    const float* z   = (const float*)d_in[0];   // [16,512,32,32]
    const float* emb = (const float*)d_in[1];   // [2048,512]
    char* ws = (char*)d_ws;
    __hip_bfloat16* zb   = (__hip_bfloat16*)(ws + WS_ZB);
    __hip_bfloat16* eb   = (__hip_bfloat16*)(ws + WS_EB);
    float*          esq  = (float*)(ws + WS_ESQ);
    unsigned int*   minb = (unsigned int*)(ws + WS_MINB);
    float*          pz   = (float*)(ws + WS_PZ);
    float*          parts= (float*)(ws + WS_PARTS);
    unsigned int*   cnt2 = (unsigned int*)(ws + WS_CNT2);
    float* out = (float*)d_out;

    kp <<<4096, 256, 0, stream>>>(z, emb, zb, eb, esq, pz, minb, cnt2);
    kg <<< 512, 512, 0, stream>>>(zb, eb, esq, minb);
    ko3<<<1024, 256, 0, stream>>>(emb, minb, pz, out, parts, cnt2);
}